// Round 2
// baseline (702.322 us; speedup 1.0000x reference)
//
#include <hip/hip_runtime.h>
#include <hip/hip_bf16.h>

// TopKPool: N=8192 nodes, F=256 features, k=4096 kept.
// out = [X_pooled (4096x256 f32) | A_pooled (4096x4096 f32)]
// A_pooled = A[idx,:] @ A[:,idx] (0.275 TFLOP) instead of (A@A)[idx][:,idx].
// Round 5: (a) gemm_fp8 was LDS-BW-bound (109us LDS pole vs 59us MFMA pole,
// MfmaUtil pinned 32%) -> A-fragments now load DIRECT global->reg (contiguous
// 2x16B per lane, L1/L2-served, reg-double-buffered one tile ahead); only B
// stays LDS-staged. LDS traffic per block-tile 96KB -> 48KB.
// (b) gather_both: 16B dwordx4 stores (was 8x 4B scattered stores/thread),
// tile pad [64][68] so row reads are b128. (c) topk pass-1 histogram: per-wave
// private bins (normal-dist scores concentrate top byte -> serialized LDS
// atomics on ~4 bins; 16 wave-private copies cut contention 16x).

#define N_NODES 8192
#define F_DIM   256
#define K_SEL   4096

typedef float floatx4 __attribute__((ext_vector_type(4)));
typedef int   intx4   __attribute__((ext_vector_type(4)));
typedef int   intx8   __attribute__((ext_vector_type(8)));

__device__ __forceinline__ void async_copy16(const void* g, void* l) {
  __builtin_amdgcn_global_load_lds((const __attribute__((address_space(1))) void*)g,
                                   (__attribute__((address_space(3))) void*)l,
                                   16, 0, 0);
}

// ---------------- y = X @ (p / ||p||) : one wave per row ----------------
__global__ __launch_bounds__(256) void compute_y(const float* __restrict__ X,
                                                 const float* __restrict__ p,
                                                 float* __restrict__ y) {
  __shared__ __align__(16) float s_p[F_DIM];
  __shared__ float s_part[4];
  __shared__ float s_inv;
  const int tid = threadIdx.x;
  float pv = p[tid];
  s_p[tid] = pv;
  float sq = pv * pv;
  #pragma unroll
  for (int off = 32; off > 0; off >>= 1) sq += __shfl_down(sq, off, 64);
  if ((tid & 63) == 0) s_part[tid >> 6] = sq;
  __syncthreads();
  if (tid == 0) s_inv = rsqrtf(s_part[0] + s_part[1] + s_part[2] + s_part[3]);
  __syncthreads();
  const int wave = tid >> 6, lane = tid & 63;
  const int row = blockIdx.x * 4 + wave;
  const float4* xr = (const float4*)(X + (size_t)row * F_DIM);
  const float4* pr = (const float4*)s_p;
  float4 xv = xr[lane];
  float4 pw = pr[lane];
  float d = xv.x * pw.x + xv.y * pw.y + xv.z * pw.z + xv.w * pw.w;
  #pragma unroll
  for (int off = 32; off > 0; off >>= 1) d += __shfl_down(d, off, 64);
  if (lane == 0) y[row] = d * s_inv;
}

// ---------------- exact top-k via radix-256 select ----------------
// rank[i] = position among kept nodes in ascending-index order, or -1.
// Ties at threshold keep lowest indices (matches top_k stability + sort).

__device__ __forceinline__ unsigned block_exscan_fast(unsigned tv, unsigned* wred,
                                                      int tid, int lane, int wid) {
  unsigned v = tv;
  #pragma unroll
  for (int o = 1; o < 64; o <<= 1) {
    unsigned n = __shfl_up(v, o, 64);
    if (lane >= o) v += n;
  }
  if (lane == 63) wred[wid] = v;
  __syncthreads();
  unsigned off = 0;
  #pragma unroll
  for (int w = 0; w < 16; ++w) off += (w < wid) ? wred[w] : 0u;
  __syncthreads();  // wred reused by caller / next call
  return off + v - tv;
}

__global__ __launch_bounds__(1024) void topk_radix(const float* __restrict__ y,
                                                   int* __restrict__ rank) {
  __shared__ unsigned keys[N_NODES];     // 32 KB
  __shared__ unsigned histw[256 * 16];   // 16 KB wave-private histograms
  __shared__ unsigned wred[16];
  __shared__ unsigned s_pref, s_krem;
  const int tid = threadIdx.x;
  const int lane = tid & 63;
  const int wid = tid >> 6;
  for (int i = tid; i < N_NODES; i += 1024) {
    unsigned u = __float_as_uint(y[i]);
    keys[i] = (u & 0x80000000u) ? ~u : (u | 0x80000000u);  // monotone map
  }
  if (tid == 0) { s_pref = 0u; s_krem = (unsigned)K_SEL; }
  __syncthreads();

  // 4 passes over 8-bit digits, MSB first.
  #pragma unroll 1
  for (int shift = 24; shift >= 0; shift -= 8) {
    #pragma unroll
    for (int i = 0; i < 4; ++i) histw[tid + i * 1024] = 0u;
    const unsigned pref = s_pref;
    const unsigned krem = s_krem;
    __syncthreads();
    const unsigned pmask = (shift == 24) ? 0u : (0xFFFFFFFFu << (shift + 8));
    for (int i = tid; i < N_NODES; i += 1024) {
      unsigned k = keys[i];
      if ((k & pmask) == pref)
        atomicAdd(&histw[(((k >> shift) & 255u) << 4) + wid], 1u);
    }
    __syncthreads();
    unsigned hb = 0, v = 0;
    if (tid < 256) {
      const int b = 255 - tid;
      #pragma unroll
      for (int w = 0; w < 16; ++w) hb += histw[(b << 4) + w];
      v = hb;
    }
    #pragma unroll
    for (int o = 1; o < 64; o <<= 1) {
      unsigned n = __shfl_up(v, o, 64);
      if (lane >= o) v += n;
    }
    if (tid < 256 && lane == 63) wred[wid] = v;
    __syncthreads();
    if (tid < 256) {
      unsigned off = 0;
      #pragma unroll
      for (int w = 0; w < 4; ++w) off += (w < wid) ? wred[w] : 0u;
      const unsigned cge = v + off;              // #(prefix match, digit >= b)
      const unsigned b = 255u - (unsigned)tid;
      const unsigned cgt = cge - hb;             // #(prefix match, digit > b)
      if (cgt < krem && cge >= krem) {           // unique winning bucket
        s_pref = pref | (b << shift);
        s_krem = krem - cgt;
      }
    }
    __syncthreads();
  }

  const unsigned T = s_pref;        // exact K-th largest key value
  const unsigned need_eq = s_krem;  // how many ==T keys to keep (lowest idx)

  const int base = tid << 3;
  unsigned e[8], g[8], te = 0;
  #pragma unroll
  for (int j = 0; j < 8; ++j) {
    unsigned k = keys[base + j];
    e[j] = (k == T) ? 1u : 0u;
    g[j] = (k > T) ? 1u : 0u;
    te += e[j];
  }
  unsigned eqr = block_exscan_fast(te, wred, tid, lane, wid);
  unsigned keep[8], tk = 0;
  #pragma unroll
  for (int j = 0; j < 8; ++j) {
    unsigned kp = g[j] | (e[j] & ((eqr < need_eq) ? 1u : 0u));
    eqr += e[j];
    keep[j] = kp;
    tk += kp;
  }
  unsigned pos = block_exscan_fast(tk, wred, tid, lane, wid);
  #pragma unroll
  for (int j = 0; j < 8; ++j) {
    if (keep[j]) { rank[base + j] = (int)pos; pos++; }
    else rank[base + j] = -1;
  }
}

// ---------------- fused gather -> fp8: one pass over A ----------------
// Abf8[rank[r], c] = e4m3(A[r, c])   (selected rows, K contiguous)
// Bt8 [rank[c], r] = e4m3(A[r, c])   (selected cols, transposed)
__global__ __launch_bounds__(256) void gather_both(const float* __restrict__ A,
                                                   const int* __restrict__ rank,
                                                   unsigned char* __restrict__ Abf8,
                                                   unsigned char* __restrict__ Bt8) {
  __shared__ float tile[64][68];   // pad 68: rows 16B-aligned, col reads ~2-way
  __shared__ int rr_[64], rc_[64];
  const int tid = threadIdx.x;
  const int r0 = blockIdx.y << 6, c0 = blockIdx.x << 6;
  if (tid < 64) rr_[tid] = rank[r0 + tid];
  else if (tid < 128) rc_[tid - 64] = rank[c0 + tid - 64];
  const int trow = tid >> 4, tc4 = (tid & 15) << 2;
  #pragma unroll
  for (int i = 0; i < 4; ++i) {
    const float4 v = *(const float4*)(A + (size_t)(r0 + trow + i * 16) * N_NODES + c0 + tc4);
    *(float4*)&tile[trow + i * 16][tc4] = v;
  }
  __syncthreads();
  // rows -> Abf8: one 16B store per thread (row tid>>2, 16 cols at (tid&3)*16)
  {
    const int tr = tid >> 2, qc = (tid & 3) << 4;
    const int rk = rr_[tr];
    if (rk >= 0) {
      intx4 o;
      #pragma unroll
      for (int jj = 0; jj < 4; ++jj) {
        float4 f = *(const float4*)&tile[tr][qc + jj * 4];
        int v = __builtin_amdgcn_cvt_pk_fp8_f32(f.x, f.y, 0, false);
        v = __builtin_amdgcn_cvt_pk_fp8_f32(f.z, f.w, v, true);
        o[jj] = v;
      }
      *(intx4*)(Abf8 + (size_t)rk * N_NODES + c0 + qc) = o;
    }
  }
  // cols -> Bt8: one 16B store per thread (col tid>>2, 16 rows at (tid&3)*16)
  {
    const int tc = tid >> 2, qr = (tid & 3) << 4;
    const int rk = rc_[tc];
    if (rk >= 0) {
      intx4 o;
      #pragma unroll
      for (int jj = 0; jj < 4; ++jj) {
        float a0 = tile[qr + jj * 4 + 0][tc];
        float a1 = tile[qr + jj * 4 + 1][tc];
        float a2 = tile[qr + jj * 4 + 2][tc];
        float a3 = tile[qr + jj * 4 + 3][tc];
        int v = __builtin_amdgcn_cvt_pk_fp8_f32(a0, a1, 0, false);
        v = __builtin_amdgcn_cvt_pk_fp8_f32(a2, a3, v, true);
        o[jj] = v;
      }
      *(intx4*)(Bt8 + (size_t)rk * N_NODES + r0 + qr) = o;
    }
  }
}

// ---------------- X_pooled[rank[i],:] = X[i,:] * tanh(y[i]) ----------------
__global__ __launch_bounds__(256) void x_pool(const float* __restrict__ X,
                                              const float* __restrict__ y,
                                              const int* __restrict__ rank,
                                              float* __restrict__ out0) {
  const int i = blockIdx.x;
  const int r = rank[i];
  if (r < 0) return;
  const float g = tanhf(y[i]);
  out0[(size_t)r * F_DIM + threadIdx.x] = X[(size_t)i * F_DIM + threadIdx.x] * g;
}

// ---------------- C[m,n] = sum_k A8[m,k] * B8[n,k] (fp8 MX, scale=1.0) ----------------
// A-fragments: direct global->reg (2x dwordx4/lane, 16 rows x 64B cache lines
// per instr), register-double-buffered one K-tile ahead. B: LDS-staged via
// global_load_lds with 16B-subchunk XOR swizzle, double-buffered. Counted
// vmcnt(12) = the 12 just-issued next-tile ops (4 B-DMA + 8 A-loads) stay in
// flight across the barrier; current tile's 12 are drained.
#define BM  128
#define BN  128
#define BKB 128  // K elements (=bytes) per tile
#define BBUF (BN * BKB)

#define GEMM_PREFETCH(bufsel, av, ktn)                                          \
  {                                                                             \
    _Pragma("unroll")                                                           \
    for (int i = 0; i < 4; ++i)                                                 \
      async_copy16(Bg[i] + (ktn), (char*)sB + (bufsel) * BBUF + ldsOff[i]);     \
    _Pragma("unroll")                                                           \
    for (int t = 0; t < 4; ++t) {                                               \
      intx4 lo = *(const intx4*)(Agp[t] + (ktn));                               \
      intx4 hi = *(const intx4*)(Agp[t] + (ktn) + 16);                          \
      av[t] = __builtin_shufflevector(lo, hi, 0, 1, 2, 3, 4, 5, 6, 7);          \
    }                                                                           \
  }

#define GEMM_COMPUTE(bufbase, av)                                               \
  {                                                                             \
    const char* bB = (const char*)(bufbase);                                    \
    intx8 bv[4];                                                                \
    _Pragma("unroll")                                                           \
    for (int t = 0; t < 4; ++t) {                                               \
      intx4 lo = *(const intx4*)(bB + offBlo[t]);                               \
      intx4 hi = *(const intx4*)(bB + offBhi[t]);                               \
      bv[t] = __builtin_shufflevector(lo, hi, 0, 1, 2, 3, 4, 5, 6, 7);          \
    }                                                                           \
    __builtin_amdgcn_s_setprio(1);                                              \
    _Pragma("unroll")                                                           \
    for (int tm = 0; tm < 4; ++tm)                                              \
      _Pragma("unroll")                                                         \
      for (int tn = 0; tn < 4; ++tn)                                            \
        acc[tm][tn] = __builtin_amdgcn_mfma_scale_f32_16x16x128_f8f6f4(         \
            av[tm], bv[tn], acc[tm][tn],                                        \
            0, 0, 0, 0x7F7F7F7F, 0, 0x7F7F7F7F);                                \
    __builtin_amdgcn_s_setprio(0);                                              \
  }

#define GEMM_BARRIER() asm volatile("s_barrier" ::: "memory")

__global__ __launch_bounds__(256, 2) void gemm_fp8(const unsigned char* __restrict__ A,
                                                   const unsigned char* __restrict__ B,
                                                   float* __restrict__ C) {
  const int Kd = N_NODES;  // 8192
  const int Nd = K_SEL;    // 4096
  __shared__ unsigned char sB[2][BBUF];  // 32 KB
  const int tid = threadIdx.x;
  const int wave = tid >> 6, lane = tid & 63;
  const int m0 = blockIdx.x * BM, n0 = blockIdx.y * BN;
  const int wm = (wave >> 1) * 64, wn = (wave & 1) * 64;
  const int l15 = lane & 15, q = lane >> 4;

  // B staging: copy i handles 16B slot S = i*256 + tid; swizzle on global src
  const unsigned char* Bg[4];
  int ldsOff[4];
  #pragma unroll
  for (int i = 0; i < 4; ++i) {
    int S = i * 256 + tid;
    int r = S >> 3;
    int sg = (S & 7) ^ (r & 7);
    Bg[i] = B + (size_t)(n0 + r) * Kd + sg * 16;
    ldsOff[i] = i * 4096 + wave * 1024;
  }

  // A direct: lane (l15,q) of fragment t loads row m0+wm+t*16+l15, bytes q*32..+32
  const unsigned char* Agp[4];
  #pragma unroll
  for (int t = 0; t < 4; ++t)
    Agp[t] = A + (size_t)(m0 + wm + t * 16 + l15) * Kd + q * 32;

  // B ds_read offsets (XOR-swizzled slots)
  int offBlo[4], offBhi[4];
  #pragma unroll
  for (int t = 0; t < 4; ++t) {
    int RB = wn + t * 16 + l15;
    offBlo[t] = RB * 128 + (((2 * q) ^ (RB & 7)) << 4);
    offBhi[t] = RB * 128 + (((2 * q + 1) ^ (RB & 7)) << 4);
  }

  floatx4 acc[4][4] = {};
  intx8 avA[4], avB[4];

  // prologue: tile 0 -> buf0 + avA   (12 VMEM ops outstanding)
  GEMM_PREFETCH(0, avA, 0);

  int kt = 0;
  #pragma unroll 1
  for (int it = 0; it < 32; ++it) {
    // even tile: compute buf0/avA, prefetch tile kt+BKB -> buf1/avB
    GEMM_PREFETCH(1, avB, kt + BKB);
    asm volatile("s_waitcnt vmcnt(12)" ::: "memory");  // drain current tile's 12
    GEMM_BARRIER();
    GEMM_COMPUTE((const char*)sB, avA);
    asm volatile("s_waitcnt lgkmcnt(0)" ::: "memory");
    GEMM_BARRIER();
    kt += BKB;
    // odd tile: compute buf1/avB, prefetch -> buf0/avA (except final tile)
    if (it < 31) {
      GEMM_PREFETCH(0, avA, kt + BKB);
      asm volatile("s_waitcnt vmcnt(12)" ::: "memory");
    } else {
      asm volatile("s_waitcnt vmcnt(0)" ::: "memory");
    }
    GEMM_BARRIER();
    GEMM_COMPUTE((const char*)sB + BBUF, avB);
    asm volatile("s_waitcnt lgkmcnt(0)" ::: "memory");
    GEMM_BARRIER();
    kt += BKB;
  }

  // C/D layout (shape-determined): col = lane&15, row = (lane>>4)*4 + reg
  const int cm = (lane >> 4) * 4;
  const int cn = lane & 15;
  #pragma unroll
  for (int tm = 0; tm < 4; ++tm)
    #pragma unroll
    for (int tn = 0; tn < 4; ++tn) {
      float* cp = C + (size_t)(m0 + wm + tm * 16 + cm) * Nd + (n0 + wn + tn * 16 + cn);
      #pragma unroll
      for (int r = 0; r < 4; ++r) cp[(size_t)r * Nd] = acc[tm][tn][r];
    }
}

extern "C" void kernel_launch(void* const* d_in, const int* in_sizes, int n_in,
                              void* d_out, int out_size, void* d_ws, size_t ws_size,
                              hipStream_t stream) {
  const float* X = (const float*)d_in[0];
  const float* A = (const float*)d_in[1];
  const float* p = (const float*)d_in[2];
  float* out0 = (float*)d_out;                      // X_pooled 4096x256
  float* out1 = out0 + (size_t)K_SEL * F_DIM;       // A_pooled 4096x4096

  // ws layout: y (32KB) | rank (32KB) | Abf8 (32MB) | Bt8 (32MB)
  char* ws = (char*)d_ws;
  float* y = (float*)ws;
  int* rank = (int*)(ws + 32768);
  unsigned char* Abf8 = (unsigned char*)(ws + 65536);
  unsigned char* Bt8 = Abf8 + (size_t)K_SEL * N_NODES;

  compute_y<<<N_NODES / 4, 256, 0, stream>>>(X, p, y);
  topk_radix<<<1, 1024, 0, stream>>>(y, rank);
  x_pool<<<N_NODES, 256, 0, stream>>>(X, y, rank, out0);
  gather_both<<<dim3(N_NODES / 64, N_NODES / 64), 256, 0, stream>>>(A, rank, Abf8, Bt8);
  gemm_fp8<<<dim3(K_SEL / BM, K_SEL / BN), 256, 0, stream>>>(Abf8, Bt8, out1);
}

// Round 3
// 557.932 us; speedup vs baseline: 1.2588x; 1.2588x over previous
//
#include <hip/hip_runtime.h>
#include <hip/hip_bf16.h>

// TopKPool: N=8192 nodes, F=256 features, k=4096 kept.
// out = [X_pooled (4096x256 f32) | A_pooled (4096x4096 f32)]
// A_pooled = A[idx,:] @ A[:,idx] (0.275 TFLOP) instead of (A@A)[idx][:,idx].
// Round 6: revert R5's A-direct-reg experiment (global scatter throttled VMEM:
// 315us, MfmaUtil 17%). New gemm: 32x32x64 MFMA so K-slab = 16KB and a 4-slot
// LDS ring (64KB) gives TRUE depth-3 pipelining (issue slab t+3, vmcnt(12) --
// 3 slabs in flight across barriers; R1's depth-1 dbuf was null because HBM
// latency ~900cy > one-round cover). Conflict-free ds_read swizzle
// s2^=(row>>1)&3 (8-lane groups bijective over bank-quads). XCD-chunked block
// swizzle: A+B (64MB) fit L3 but FETCH was 178MB -- give each XCD 4 contiguous
// M-panels (4MB = L2-resident A), stream B once.

#define N_NODES 8192
#define F_DIM   256
#define K_SEL   4096

typedef float floatx4  __attribute__((ext_vector_type(4)));
typedef float floatx16 __attribute__((ext_vector_type(16)));
typedef int   intx4    __attribute__((ext_vector_type(4)));
typedef int   intx8    __attribute__((ext_vector_type(8)));

__device__ __forceinline__ void async_copy16(const void* g, void* l) {
  __builtin_amdgcn_global_load_lds((const __attribute__((address_space(1))) void*)g,
                                   (__attribute__((address_space(3))) void*)l,
                                   16, 0, 0);
}

// ---------------- y = X @ (p / ||p||) : one wave per row ----------------
__global__ __launch_bounds__(256) void compute_y(const float* __restrict__ X,
                                                 const float* __restrict__ p,
                                                 float* __restrict__ y) {
  __shared__ __align__(16) float s_p[F_DIM];
  __shared__ float s_part[4];
  __shared__ float s_inv;
  const int tid = threadIdx.x;
  float pv = p[tid];
  s_p[tid] = pv;
  float sq = pv * pv;
  #pragma unroll
  for (int off = 32; off > 0; off >>= 1) sq += __shfl_down(sq, off, 64);
  if ((tid & 63) == 0) s_part[tid >> 6] = sq;
  __syncthreads();
  if (tid == 0) s_inv = rsqrtf(s_part[0] + s_part[1] + s_part[2] + s_part[3]);
  __syncthreads();
  const int wave = tid >> 6, lane = tid & 63;
  const int row = blockIdx.x * 4 + wave;
  const float4* xr = (const float4*)(X + (size_t)row * F_DIM);
  const float4* pr = (const float4*)s_p;
  float4 xv = xr[lane];
  float4 pw = pr[lane];
  float d = xv.x * pw.x + xv.y * pw.y + xv.z * pw.z + xv.w * pw.w;
  #pragma unroll
  for (int off = 32; off > 0; off >>= 1) d += __shfl_down(d, off, 64);
  if (lane == 0) y[row] = d * s_inv;
}

// ---------------- exact top-k via radix-256 select ----------------
// rank[i] = position among kept nodes in ascending-index order, or -1.
// Ties at threshold keep lowest indices (matches top_k stability + sort).

__device__ __forceinline__ unsigned block_exscan_fast(unsigned tv, unsigned* wred,
                                                      int tid, int lane, int wid) {
  unsigned v = tv;
  #pragma unroll
  for (int o = 1; o < 64; o <<= 1) {
    unsigned n = __shfl_up(v, o, 64);
    if (lane >= o) v += n;
  }
  if (lane == 63) wred[wid] = v;
  __syncthreads();
  unsigned off = 0;
  #pragma unroll
  for (int w = 0; w < 16; ++w) off += (w < wid) ? wred[w] : 0u;
  __syncthreads();  // wred reused by caller / next call
  return off + v - tv;
}

__global__ __launch_bounds__(1024) void topk_radix(const float* __restrict__ y,
                                                   int* __restrict__ rank) {
  __shared__ unsigned keys[N_NODES];     // 32 KB
  __shared__ unsigned histw[256 * 16];   // 16 KB wave-private histograms
  __shared__ unsigned wred[16];
  __shared__ unsigned s_pref, s_krem;
  const int tid = threadIdx.x;
  const int lane = tid & 63;
  const int wid = tid >> 6;
  for (int i = tid; i < N_NODES; i += 1024) {
    unsigned u = __float_as_uint(y[i]);
    keys[i] = (u & 0x80000000u) ? ~u : (u | 0x80000000u);  // monotone map
  }
  if (tid == 0) { s_pref = 0u; s_krem = (unsigned)K_SEL; }
  __syncthreads();

  // 4 passes over 8-bit digits, MSB first.
  #pragma unroll 1
  for (int shift = 24; shift >= 0; shift -= 8) {
    #pragma unroll
    for (int i = 0; i < 4; ++i) histw[tid + i * 1024] = 0u;
    const unsigned pref = s_pref;
    const unsigned krem = s_krem;
    __syncthreads();
    const unsigned pmask = (shift == 24) ? 0u : (0xFFFFFFFFu << (shift + 8));
    for (int i = tid; i < N_NODES; i += 1024) {
      unsigned k = keys[i];
      if ((k & pmask) == pref)
        atomicAdd(&histw[(((k >> shift) & 255u) << 4) + wid], 1u);
    }
    __syncthreads();
    unsigned hb = 0, v = 0;
    if (tid < 256) {
      const int b = 255 - tid;
      #pragma unroll
      for (int w = 0; w < 16; ++w) hb += histw[(b << 4) + w];
      v = hb;
    }
    #pragma unroll
    for (int o = 1; o < 64; o <<= 1) {
      unsigned n = __shfl_up(v, o, 64);
      if (lane >= o) v += n;
    }
    if (tid < 256 && lane == 63) wred[wid] = v;
    __syncthreads();
    if (tid < 256) {
      unsigned off = 0;
      #pragma unroll
      for (int w = 0; w < 4; ++w) off += (w < wid) ? wred[w] : 0u;
      const unsigned cge = v + off;              // #(prefix match, digit >= b)
      const unsigned b = 255u - (unsigned)tid;
      const unsigned cgt = cge - hb;             // #(prefix match, digit > b)
      if (cgt < krem && cge >= krem) {           // unique winning bucket
        s_pref = pref | (b << shift);
        s_krem = krem - cgt;
      }
    }
    __syncthreads();
  }

  const unsigned T = s_pref;        // exact K-th largest key value
  const unsigned need_eq = s_krem;  // how many ==T keys to keep (lowest idx)

  const int base = tid << 3;
  unsigned e[8], g[8], te = 0;
  #pragma unroll
  for (int j = 0; j < 8; ++j) {
    unsigned k = keys[base + j];
    e[j] = (k == T) ? 1u : 0u;
    g[j] = (k > T) ? 1u : 0u;
    te += e[j];
  }
  unsigned eqr = block_exscan_fast(te, wred, tid, lane, wid);
  unsigned keep[8], tk = 0;
  #pragma unroll
  for (int j = 0; j < 8; ++j) {
    unsigned kp = g[j] | (e[j] & ((eqr < need_eq) ? 1u : 0u));
    eqr += e[j];
    keep[j] = kp;
    tk += kp;
  }
  unsigned pos = block_exscan_fast(tk, wred, tid, lane, wid);
  #pragma unroll
  for (int j = 0; j < 8; ++j) {
    if (keep[j]) { rank[base + j] = (int)pos; pos++; }
    else rank[base + j] = -1;
  }
}

// ---------------- fused gather -> fp8: one pass over A ----------------
// Abf8[rank[r], c] = e4m3(A[r, c])   (selected rows, K contiguous)
// Bt8 [rank[c], r] = e4m3(A[r, c])   (selected cols, transposed)
__global__ __launch_bounds__(256) void gather_both(const float* __restrict__ A,
                                                   const int* __restrict__ rank,
                                                   unsigned char* __restrict__ Abf8,
                                                   unsigned char* __restrict__ Bt8) {
  __shared__ float tile[64][68];   // pad 68: rows 16B-aligned, col reads ~2-way
  __shared__ int rr_[64], rc_[64];
  const int tid = threadIdx.x;
  const int r0 = blockIdx.y << 6, c0 = blockIdx.x << 6;
  if (tid < 64) rr_[tid] = rank[r0 + tid];
  else if (tid < 128) rc_[tid - 64] = rank[c0 + tid - 64];
  const int trow = tid >> 4, tc4 = (tid & 15) << 2;
  #pragma unroll
  for (int i = 0; i < 4; ++i) {
    const float4 v = *(const float4*)(A + (size_t)(r0 + trow + i * 16) * N_NODES + c0 + tc4);
    *(float4*)&tile[trow + i * 16][tc4] = v;
  }
  __syncthreads();
  // rows -> Abf8: one 16B store per thread (row tid>>2, 16 cols at (tid&3)*16)
  {
    const int tr = tid >> 2, qc = (tid & 3) << 4;
    const int rk = rr_[tr];
    if (rk >= 0) {
      intx4 o;
      #pragma unroll
      for (int jj = 0; jj < 4; ++jj) {
        float4 f = *(const float4*)&tile[tr][qc + jj * 4];
        int v = __builtin_amdgcn_cvt_pk_fp8_f32(f.x, f.y, 0, false);
        v = __builtin_amdgcn_cvt_pk_fp8_f32(f.z, f.w, v, true);
        o[jj] = v;
      }
      *(intx4*)(Abf8 + (size_t)rk * N_NODES + c0 + qc) = o;
    }
  }
  // cols -> Bt8: one 16B store per thread (col tid>>2, 16 rows at (tid&3)*16)
  {
    const int tc = tid >> 2, qr = (tid & 3) << 4;
    const int rk = rc_[tc];
    if (rk >= 0) {
      intx4 o;
      #pragma unroll
      for (int jj = 0; jj < 4; ++jj) {
        float a0 = tile[qr + jj * 4 + 0][tc];
        float a1 = tile[qr + jj * 4 + 1][tc];
        float a2 = tile[qr + jj * 4 + 2][tc];
        float a3 = tile[qr + jj * 4 + 3][tc];
        int v = __builtin_amdgcn_cvt_pk_fp8_f32(a0, a1, 0, false);
        v = __builtin_amdgcn_cvt_pk_fp8_f32(a2, a3, v, true);
        o[jj] = v;
      }
      *(intx4*)(Bt8 + (size_t)rk * N_NODES + r0 + qr) = o;
    }
  }
}

// ---------------- X_pooled[rank[i],:] = X[i,:] * tanh(y[i]) ----------------
__global__ __launch_bounds__(256) void x_pool(const float* __restrict__ X,
                                              const float* __restrict__ y,
                                              const int* __restrict__ rank,
                                              float* __restrict__ out0) {
  const int i = blockIdx.x;
  const int r = rank[i];
  if (r < 0) return;
  const float g = tanhf(y[i]);
  out0[(size_t)r * F_DIM + threadIdx.x] = X[(size_t)i * F_DIM + threadIdx.x] * g;
}

// ---------------- C[m,n] = sum_k A8[m,k] * B8[n,k] (fp8 MX, scale=1.0) ----
// 32x32x64 MFMA, K-slab = 64B: ring slot = A(8KB) + B(8KB) = 16KB, RING=4
// slots = 64KB. Depth-3 pipeline: round t issues slab t+3, gates vmcnt(12)
// (slabs t+1..t+3 stay in flight across both barriers). LDS 16B-subchunk
// swizzle s2 ^= (row>>1)&3: consecutive-8-lane groups of ds_read_b128 map
// bijectively onto the 8 bank-quads (conflict-free). Staging via
// global_load_lds: linear LDS dest, inverse-swizzled global source.
#define RINGSZ 16384  // one slot: A 8KB @ +0, B 8KB @ +8192

#define G_ISSUE(t)                                                              \
  {                                                                             \
    const int ko_ = (t) * 64, rs_ = ((t) & 3) * RINGSZ;                         \
    _Pragma("unroll")                                                           \
    for (int j = 0; j < 4; ++j)                                                 \
      async_copy16(gsrc[j] + ko_, (char*)lds + rs_ + ldst[j]);                  \
  }

#define G_GATE(n)                                                               \
  {                                                                             \
    asm volatile("s_waitcnt vmcnt(" #n ")" ::: "memory");                       \
    __builtin_amdgcn_s_barrier();                                               \
    asm volatile("" ::: "memory");                                              \
  }

#define G_COMP(t)                                                               \
  {                                                                             \
    const char* bp_ = (const char*)lds + ((t) & 3) * RINGSZ;                    \
    intx8 av[2], bv[2];                                                         \
    _Pragma("unroll")                                                           \
    for (int f = 0; f < 2; ++f) {                                               \
      intx4 lo = *(const intx4*)(bp_ + offA[f][0]);                             \
      intx4 hi = *(const intx4*)(bp_ + offA[f][1]);                             \
      av[f] = __builtin_shufflevector(lo, hi, 0, 1, 2, 3, 4, 5, 6, 7);          \
      lo = *(const intx4*)(bp_ + offB[f][0]);                                   \
      hi = *(const intx4*)(bp_ + offB[f][1]);                                   \
      bv[f] = __builtin_shufflevector(lo, hi, 0, 1, 2, 3, 4, 5, 6, 7);          \
    }                                                                           \
    asm volatile("s_waitcnt lgkmcnt(0)" ::: "memory");                          \
    __builtin_amdgcn_s_setprio(1);                                              \
    _Pragma("unroll")                                                           \
    for (int tm = 0; tm < 2; ++tm)                                              \
      _Pragma("unroll")                                                         \
      for (int tn = 0; tn < 2; ++tn)                                            \
        acc[tm][tn] = __builtin_amdgcn_mfma_scale_f32_32x32x64_f8f6f4(          \
            av[tm], bv[tn], acc[tm][tn], 0, 0, 0, 0x7F7F7F7F, 0, 0x7F7F7F7F);   \
    __builtin_amdgcn_s_setprio(0);                                              \
    __builtin_amdgcn_s_barrier();                                               \
    asm volatile("" ::: "memory");                                              \
  }

__global__ __launch_bounds__(256, 2) void gemm_fp8(const unsigned char* __restrict__ A,
                                                   const unsigned char* __restrict__ B,
                                                   float* __restrict__ C) {
  const int Kd = N_NODES;  // 8192
  const int Nd = K_SEL;    // 4096
  __shared__ unsigned char lds[4 * RINGSZ];  // 64 KB
  const int tid = threadIdx.x;
  const int wave = tid >> 6, lane = tid & 63;
  // XCD-chunked swizzle: XCD x owns m-tiles 4x..4x+3 (4MB A = L2-resident),
  // streams all n-tiles. wg%8 == hardware XCD round-robin. Bijective (1024%8==0).
  const int wg = blockIdx.y * gridDim.x + blockIdx.x;
  const int xcd = wg & 7, loc = wg >> 3;
  const int m0 = (((xcd << 2) | (loc & 3))) * 128;
  const int n0 = (loc >> 2) * 128;
  const int wm = (wave >> 1) * 64, wn = (wave & 1) * 64;
  const int l31 = lane & 31, lh = lane >> 5;

  // staging: copy j in {0,1}=A slot L=j*256+tid, {2,3}=B slot L=(j-2)*256+tid.
  // slot L: row=L>>2, phys subchunk L&3 -> logical s2 = (L&3) ^ ((row>>1)&3).
  const unsigned char* gsrc[4];
  int ldst[4];
  #pragma unroll
  for (int j = 0; j < 4; ++j) {
    const int L = (j & 1) * 256 + tid;
    const int row = L >> 2;
    const int s2 = (L & 3) ^ ((row >> 1) & 3);
    const unsigned char* base =
        (j < 2) ? (A + (size_t)(m0 + row) * Kd) : (B + (size_t)(n0 + row) * Kd);
    gsrc[j] = base + s2 * 16;
    ldst[j] = ((j < 2) ? 0 : 8192) + (j & 1) * 4096 + wave * 1024;
  }

  // fragment ds_read offsets (A: rows wm+f*32+l31; B: rows wn+f*32+l31;
  // k16 = lh*2 + h; swizzled subchunk = k16 ^ ((row>>1)&3))
  int offA[2][2], offB[2][2];
  #pragma unroll
  for (int f = 0; f < 2; ++f) {
    const int ra = wm + f * 32 + l31;
    const int rb = wn + f * 32 + l31;
    #pragma unroll
    for (int h = 0; h < 2; ++h) {
      const int k16 = lh * 2 + h;
      offA[f][h] = ra * 64 + ((k16 ^ ((ra >> 1) & 3)) << 4);
      offB[f][h] = 8192 + rb * 64 + ((k16 ^ ((rb >> 1) & 3)) << 4);
    }
  }

  floatx16 acc[2][2] = {};

  // prologue: 3 slabs in flight
  G_ISSUE(0);
  G_ISSUE(1);
  G_ISSUE(2);
  #pragma unroll 1
  for (int t = 0; t < 125; ++t) {
    G_ISSUE(t + 3);
    G_GATE(12);
    G_COMP(t);
  }
  G_GATE(8);
  G_COMP(125);
  G_GATE(4);
  G_COMP(126);
  G_GATE(0);
  G_COMP(127);

  // C/D 32x32: col = lane&31, row = (reg&3) + 8*(reg>>2) + 4*(lane>>5)
  #pragma unroll
  for (int tm = 0; tm < 2; ++tm)
    #pragma unroll
    for (int tn = 0; tn < 2; ++tn) {
      float* cp = C + (size_t)(m0 + wm + tm * 32) * Nd + n0 + wn + tn * 32 + l31;
      #pragma unroll
      for (int r = 0; r < 16; ++r) {
        const int crow = (r & 3) + 8 * (r >> 2) + 4 * lh;
        cp[(size_t)crow * Nd] = acc[tm][tn][r];
      }
    }
}

extern "C" void kernel_launch(void* const* d_in, const int* in_sizes, int n_in,
                              void* d_out, int out_size, void* d_ws, size_t ws_size,
                              hipStream_t stream) {
  const float* X = (const float*)d_in[0];
  const float* A = (const float*)d_in[1];
  const float* p = (const float*)d_in[2];
  float* out0 = (float*)d_out;                      // X_pooled 4096x256
  float* out1 = out0 + (size_t)K_SEL * F_DIM;       // A_pooled 4096x4096

  // ws layout: y (32KB) | rank (32KB) | Abf8 (32MB) | Bt8 (32MB)
  char* ws = (char*)d_ws;
  float* y = (float*)ws;
  int* rank = (int*)(ws + 32768);
  unsigned char* Abf8 = (unsigned char*)(ws + 65536);
  unsigned char* Bt8 = Abf8 + (size_t)K_SEL * N_NODES;

  compute_y<<<N_NODES / 4, 256, 0, stream>>>(X, p, y);
  topk_radix<<<1, 1024, 0, stream>>>(y, rank);
  x_pool<<<N_NODES, 256, 0, stream>>>(X, y, rank, out0);
  gather_both<<<dim3(N_NODES / 64, N_NODES / 64), 256, 0, stream>>>(A, rank, Abf8, Bt8);
  gemm_fp8<<<dim3(K_SEL / 128, K_SEL / 128), 256, 0, stream>>>(Abf8, Bt8, out1);
}

// Round 4
// 550.466 us; speedup vs baseline: 1.2759x; 1.0136x over previous
//
#include <hip/hip_runtime.h>
#include <hip/hip_bf16.h>

// TopKPool: N=8192 nodes, F=256 features, k=4096 kept.
// out = [X_pooled (4096x256 f32) | A_pooled (4096x4096 f32)]
// A_pooled = A[idx,:] @ A[:,idx] (0.275 TFLOP) instead of (A@A)[idx][:,idx].
// Round 7: gemm arithmetic-intensity fix. R6 analysis: per 128^2-block slab,
// LDS moved 48KB (384cy) vs 275cy MFMA -> matrix pipe capped ~40% regardless
// of pipelining (SQ_LDS_BANK_CONFLICT == 4cy x #b128 exactly = structural
// floor, swizzle already optimal). New: 256x256 block, 8 waves in 4x2 grid,
// wave tile 64x128 (av[2] x bv[4]): per slab 96KB read + 32KB write (~1000cy)
// vs 64 MFMA x 17.2 = 1100cy -> MFMA-bound. Ring-2 (64KB), round ~1400cy >
// 900cy HBM latency so depth-1 lookahead suffices. Other kernels unchanged.

#define N_NODES 8192
#define F_DIM   256
#define K_SEL   4096

typedef float floatx4  __attribute__((ext_vector_type(4)));
typedef float floatx16 __attribute__((ext_vector_type(16)));
typedef int   intx4    __attribute__((ext_vector_type(4)));
typedef int   intx8    __attribute__((ext_vector_type(8)));

__device__ __forceinline__ void async_copy16(const void* g, void* l) {
  __builtin_amdgcn_global_load_lds((const __attribute__((address_space(1))) void*)g,
                                   (__attribute__((address_space(3))) void*)l,
                                   16, 0, 0);
}

// ---------------- y = X @ (p / ||p||) : one wave per row ----------------
__global__ __launch_bounds__(256) void compute_y(const float* __restrict__ X,
                                                 const float* __restrict__ p,
                                                 float* __restrict__ y) {
  __shared__ __align__(16) float s_p[F_DIM];
  __shared__ float s_part[4];
  __shared__ float s_inv;
  const int tid = threadIdx.x;
  float pv = p[tid];
  s_p[tid] = pv;
  float sq = pv * pv;
  #pragma unroll
  for (int off = 32; off > 0; off >>= 1) sq += __shfl_down(sq, off, 64);
  if ((tid & 63) == 0) s_part[tid >> 6] = sq;
  __syncthreads();
  if (tid == 0) s_inv = rsqrtf(s_part[0] + s_part[1] + s_part[2] + s_part[3]);
  __syncthreads();
  const int wave = tid >> 6, lane = tid & 63;
  const int row = blockIdx.x * 4 + wave;
  const float4* xr = (const float4*)(X + (size_t)row * F_DIM);
  const float4* pr = (const float4*)s_p;
  float4 xv = xr[lane];
  float4 pw = pr[lane];
  float d = xv.x * pw.x + xv.y * pw.y + xv.z * pw.z + xv.w * pw.w;
  #pragma unroll
  for (int off = 32; off > 0; off >>= 1) d += __shfl_down(d, off, 64);
  if (lane == 0) y[row] = d * s_inv;
}

// ---------------- exact top-k via radix-256 select ----------------
// rank[i] = position among kept nodes in ascending-index order, or -1.
// Ties at threshold keep lowest indices (matches top_k stability + sort).

__device__ __forceinline__ unsigned block_exscan_fast(unsigned tv, unsigned* wred,
                                                      int tid, int lane, int wid) {
  unsigned v = tv;
  #pragma unroll
  for (int o = 1; o < 64; o <<= 1) {
    unsigned n = __shfl_up(v, o, 64);
    if (lane >= o) v += n;
  }
  if (lane == 63) wred[wid] = v;
  __syncthreads();
  unsigned off = 0;
  #pragma unroll
  for (int w = 0; w < 16; ++w) off += (w < wid) ? wred[w] : 0u;
  __syncthreads();  // wred reused by caller / next call
  return off + v - tv;
}

__global__ __launch_bounds__(1024) void topk_radix(const float* __restrict__ y,
                                                   int* __restrict__ rank) {
  __shared__ unsigned keys[N_NODES];     // 32 KB
  __shared__ unsigned histw[256 * 16];   // 16 KB wave-private histograms
  __shared__ unsigned wred[16];
  __shared__ unsigned s_pref, s_krem;
  const int tid = threadIdx.x;
  const int lane = tid & 63;
  const int wid = tid >> 6;
  for (int i = tid; i < N_NODES; i += 1024) {
    unsigned u = __float_as_uint(y[i]);
    keys[i] = (u & 0x80000000u) ? ~u : (u | 0x80000000u);  // monotone map
  }
  if (tid == 0) { s_pref = 0u; s_krem = (unsigned)K_SEL; }
  __syncthreads();

  // 4 passes over 8-bit digits, MSB first.
  #pragma unroll 1
  for (int shift = 24; shift >= 0; shift -= 8) {
    #pragma unroll
    for (int i = 0; i < 4; ++i) histw[tid + i * 1024] = 0u;
    const unsigned pref = s_pref;
    const unsigned krem = s_krem;
    __syncthreads();
    const unsigned pmask = (shift == 24) ? 0u : (0xFFFFFFFFu << (shift + 8));
    for (int i = tid; i < N_NODES; i += 1024) {
      unsigned k = keys[i];
      if ((k & pmask) == pref)
        atomicAdd(&histw[(((k >> shift) & 255u) << 4) + wid], 1u);
    }
    __syncthreads();
    unsigned hb = 0, v = 0;
    if (tid < 256) {
      const int b = 255 - tid;
      #pragma unroll
      for (int w = 0; w < 16; ++w) hb += histw[(b << 4) + w];
      v = hb;
    }
    #pragma unroll
    for (int o = 1; o < 64; o <<= 1) {
      unsigned n = __shfl_up(v, o, 64);
      if (lane >= o) v += n;
    }
    if (tid < 256 && lane == 63) wred[wid] = v;
    __syncthreads();
    if (tid < 256) {
      unsigned off = 0;
      #pragma unroll
      for (int w = 0; w < 4; ++w) off += (w < wid) ? wred[w] : 0u;
      const unsigned cge = v + off;              // #(prefix match, digit >= b)
      const unsigned b = 255u - (unsigned)tid;
      const unsigned cgt = cge - hb;             // #(prefix match, digit > b)
      if (cgt < krem && cge >= krem) {           // unique winning bucket
        s_pref = pref | (b << shift);
        s_krem = krem - cgt;
      }
    }
    __syncthreads();
  }

  const unsigned T = s_pref;        // exact K-th largest key value
  const unsigned need_eq = s_krem;  // how many ==T keys to keep (lowest idx)

  const int base = tid << 3;
  unsigned e[8], g[8], te = 0;
  #pragma unroll
  for (int j = 0; j < 8; ++j) {
    unsigned k = keys[base + j];
    e[j] = (k == T) ? 1u : 0u;
    g[j] = (k > T) ? 1u : 0u;
    te += e[j];
  }
  unsigned eqr = block_exscan_fast(te, wred, tid, lane, wid);
  unsigned keep[8], tk = 0;
  #pragma unroll
  for (int j = 0; j < 8; ++j) {
    unsigned kp = g[j] | (e[j] & ((eqr < need_eq) ? 1u : 0u));
    eqr += e[j];
    keep[j] = kp;
    tk += kp;
  }
  unsigned pos = block_exscan_fast(tk, wred, tid, lane, wid);
  #pragma unroll
  for (int j = 0; j < 8; ++j) {
    if (keep[j]) { rank[base + j] = (int)pos; pos++; }
    else rank[base + j] = -1;
  }
}

// ---------------- fused gather -> fp8: one pass over A ----------------
// Abf8[rank[r], c] = e4m3(A[r, c])   (selected rows, K contiguous)
// Bt8 [rank[c], r] = e4m3(A[r, c])   (selected cols, transposed)
__global__ __launch_bounds__(256) void gather_both(const float* __restrict__ A,
                                                   const int* __restrict__ rank,
                                                   unsigned char* __restrict__ Abf8,
                                                   unsigned char* __restrict__ Bt8) {
  __shared__ float tile[64][68];   // pad 68: rows 16B-aligned, col reads ~2-way
  __shared__ int rr_[64], rc_[64];
  const int tid = threadIdx.x;
  const int r0 = blockIdx.y << 6, c0 = blockIdx.x << 6;
  if (tid < 64) rr_[tid] = rank[r0 + tid];
  else if (tid < 128) rc_[tid - 64] = rank[c0 + tid - 64];
  const int trow = tid >> 4, tc4 = (tid & 15) << 2;
  #pragma unroll
  for (int i = 0; i < 4; ++i) {
    const float4 v = *(const float4*)(A + (size_t)(r0 + trow + i * 16) * N_NODES + c0 + tc4);
    *(float4*)&tile[trow + i * 16][tc4] = v;
  }
  __syncthreads();
  // rows -> Abf8: one 16B store per thread (row tid>>2, 16 cols at (tid&3)*16)
  {
    const int tr = tid >> 2, qc = (tid & 3) << 4;
    const int rk = rr_[tr];
    if (rk >= 0) {
      intx4 o;
      #pragma unroll
      for (int jj = 0; jj < 4; ++jj) {
        float4 f = *(const float4*)&tile[tr][qc + jj * 4];
        int v = __builtin_amdgcn_cvt_pk_fp8_f32(f.x, f.y, 0, false);
        v = __builtin_amdgcn_cvt_pk_fp8_f32(f.z, f.w, v, true);
        o[jj] = v;
      }
      *(intx4*)(Abf8 + (size_t)rk * N_NODES + c0 + qc) = o;
    }
  }
  // cols -> Bt8: one 16B store per thread (col tid>>2, 16 rows at (tid&3)*16)
  {
    const int tc = tid >> 2, qr = (tid & 3) << 4;
    const int rk = rc_[tc];
    if (rk >= 0) {
      intx4 o;
      #pragma unroll
      for (int jj = 0; jj < 4; ++jj) {
        float a0 = tile[qr + jj * 4 + 0][tc];
        float a1 = tile[qr + jj * 4 + 1][tc];
        float a2 = tile[qr + jj * 4 + 2][tc];
        float a3 = tile[qr + jj * 4 + 3][tc];
        int v = __builtin_amdgcn_cvt_pk_fp8_f32(a0, a1, 0, false);
        v = __builtin_amdgcn_cvt_pk_fp8_f32(a2, a3, v, true);
        o[jj] = v;
      }
      *(intx4*)(Bt8 + (size_t)rk * N_NODES + r0 + qr) = o;
    }
  }
}

// ---------------- X_pooled[rank[i],:] = X[i,:] * tanh(y[i]) ----------------
__global__ __launch_bounds__(256) void x_pool(const float* __restrict__ X,
                                              const float* __restrict__ y,
                                              const int* __restrict__ rank,
                                              float* __restrict__ out0) {
  const int i = blockIdx.x;
  const int r = rank[i];
  if (r < 0) return;
  const float g = tanhf(y[i]);
  out0[(size_t)r * F_DIM + threadIdx.x] = X[(size_t)i * F_DIM + threadIdx.x] * g;
}

// ---------------- C[m,n] = sum_k A8[m,k] * B8[n,k] (fp8 MX, scale=1.0) ----
// 256x256 block, 512 threads (8 waves, grid 4M x 2N), wave tile 64x128:
// av[2] x bv[4] -> 8 MFMA per wave per K-slab(64B). Per slab: LDS read 96KB +
// DMA write 32KB (~1000cy) vs MFMA 64x17.2 = 1100cy -> MFMA-bound.
// Ring-2 LDS (2 x 32KB slots = 64KB), gate vmcnt(4): slab t+1's 4 loads per
// thread stay in flight through round t (~1400cy > HBM latency).
// 16B-subchunk swizzle s2 ^= (row>>1)&3 (same verified involution as R6).
#define SLOT 32768  // one slot: A 16KB @ +0, B 16KB @ +16384

#define G_ISSUE(t)                                                              \
  {                                                                             \
    const int ko_ = (t) * 64, rs_ = ((t) & 1) * SLOT;                           \
    _Pragma("unroll")                                                           \
    for (int j = 0; j < 4; ++j)                                                 \
      async_copy16(gsrc[j] + ko_, (char*)lds + rs_ + ldst[j]);                  \
  }

__global__ __launch_bounds__(512, 2) void gemm_fp8(const unsigned char* __restrict__ A,
                                                   const unsigned char* __restrict__ B,
                                                   float* __restrict__ C) {
  const int Kd = N_NODES;  // 8192
  const int Nd = K_SEL;    // 4096
  __shared__ unsigned char lds[2 * SLOT];  // 64 KB
  const int tid = threadIdx.x;
  const int wave = tid >> 6, lane = tid & 63;
  // XCD-chunked swizzle: 256 blocks (16x16 tiles); XCD x owns m-tiles
  // {2x, 2x+1} (512 rows x 8KB fp8 = 4MB = L2-resident A panel), streams n.
  const int wg = blockIdx.y * gridDim.x + blockIdx.x;
  const int xcd = wg & 7, loc = wg >> 3;          // loc in [0,32)
  const int m0 = (xcd * 2 + (loc & 1)) * 256;
  const int n0 = (loc >> 1) * 256;
  const int wm = (wave >> 1) * 64;                // 4 M-groups of 64
  const int wn = (wave & 1) * 128;                // 2 N-groups of 128
  const int l31 = lane & 31, lh = lane >> 5;

  // staging: j in {0,1} -> A halves, {2,3} -> B halves. Slot L = (j&1)*512+tid:
  // row = L>>2 in [0,256), phys subchunk L&3, logical s2 = (L&3)^((row>>1)&3).
  // LDS dest per wave = uniform base + lane*16 (linear); swizzle on global src.
  const unsigned char* gsrc[4];
  int ldst[4];
  #pragma unroll
  for (int j = 0; j < 4; ++j) {
    const int L = (j & 1) * 512 + tid;
    const int row = L >> 2;
    const int s2 = (L & 3) ^ ((row >> 1) & 3);
    const unsigned char* base =
        (j < 2) ? (A + (size_t)(m0 + row) * Kd) : (B + (size_t)(n0 + row) * Kd);
    gsrc[j] = base + s2 * 16;
    ldst[j] = ((j < 2) ? 0 : 16384) + (j & 1) * 8192 + wave * 1024;
  }

  // fragment ds_read offsets: lane holds row (l31), k-bytes lh*32..+32
  // (two b128 at swizzled subchunks k16 = lh*2+h).
  int offA[2][2], offB[4][2];
  #pragma unroll
  for (int f = 0; f < 2; ++f) {
    const int ra = wm + f * 32 + l31;
    #pragma unroll
    for (int h = 0; h < 2; ++h)
      offA[f][h] = ra * 64 + ((((lh * 2 + h) ^ ((ra >> 1) & 3))) << 4);
  }
  #pragma unroll
  for (int g = 0; g < 4; ++g) {
    const int rb = wn + g * 32 + l31;
    #pragma unroll
    for (int h = 0; h < 2; ++h)
      offB[g][h] = 16384 + rb * 64 + ((((lh * 2 + h) ^ ((rb >> 1) & 3))) << 4);
  }

  floatx16 acc[2][4] = {};

  G_ISSUE(0);
  #pragma unroll 1
  for (int t = 0; t < 128; ++t) {
    if (t < 127) {
      G_ISSUE(t + 1);
      asm volatile("s_waitcnt vmcnt(4)" ::: "memory");   // slab t's 4 done
    } else {
      asm volatile("s_waitcnt vmcnt(0)" ::: "memory");
    }
    __builtin_amdgcn_s_barrier();
    asm volatile("" ::: "memory");

    const char* bp = (const char*)lds + (t & 1) * SLOT;
    intx8 av[2], bv[4];
    #pragma unroll
    for (int f = 0; f < 2; ++f) {
      intx4 lo = *(const intx4*)(bp + offA[f][0]);
      intx4 hi = *(const intx4*)(bp + offA[f][1]);
      av[f] = __builtin_shufflevector(lo, hi, 0, 1, 2, 3, 4, 5, 6, 7);
    }
    #pragma unroll
    for (int g = 0; g < 4; ++g) {
      intx4 lo = *(const intx4*)(bp + offB[g][0]);
      intx4 hi = *(const intx4*)(bp + offB[g][1]);
      bv[g] = __builtin_shufflevector(lo, hi, 0, 1, 2, 3, 4, 5, 6, 7);
    }
    __builtin_amdgcn_s_setprio(1);
    #pragma unroll
    for (int tm = 0; tm < 2; ++tm)
      #pragma unroll
      for (int tn = 0; tn < 4; ++tn)
        acc[tm][tn] = __builtin_amdgcn_mfma_scale_f32_32x32x64_f8f6f4(
            av[tm], bv[tn], acc[tm][tn], 0, 0, 0, 0x7F7F7F7F, 0, 0x7F7F7F7F);
    __builtin_amdgcn_s_setprio(0);
    asm volatile("s_waitcnt lgkmcnt(0)" ::: "memory");   // slot-lifetime safety
    __builtin_amdgcn_s_barrier();
    asm volatile("" ::: "memory");
  }

  // C/D 32x32: col = lane&31, row = (reg&3) + 8*(reg>>2) + 4*(lane>>5)
  #pragma unroll
  for (int tm = 0; tm < 2; ++tm)
    #pragma unroll
    for (int tn = 0; tn < 4; ++tn) {
      float* cp = C + (size_t)(m0 + wm + tm * 32) * Nd + n0 + wn + tn * 32 + l31;
      #pragma unroll
      for (int r = 0; r < 16; ++r) {
        const int crow = (r & 3) + 8 * (r >> 2) + 4 * lh;
        cp[(size_t)crow * Nd] = acc[tm][tn][r];
      }
    }
}

extern "C" void kernel_launch(void* const* d_in, const int* in_sizes, int n_in,
                              void* d_out, int out_size, void* d_ws, size_t ws_size,
                              hipStream_t stream) {
  const float* X = (const float*)d_in[0];
  const float* A = (const float*)d_in[1];
  const float* p = (const float*)d_in[2];
  float* out0 = (float*)d_out;                      // X_pooled 4096x256
  float* out1 = out0 + (size_t)K_SEL * F_DIM;       // A_pooled 4096x4096

  // ws layout: y (32KB) | rank (32KB) | Abf8 (32MB) | Bt8 (32MB)
  char* ws = (char*)d_ws;
  float* y = (float*)ws;
  int* rank = (int*)(ws + 32768);
  unsigned char* Abf8 = (unsigned char*)(ws + 65536);
  unsigned char* Bt8 = Abf8 + (size_t)K_SEL * N_NODES;

  compute_y<<<N_NODES / 4, 256, 0, stream>>>(X, p, y);
  topk_radix<<<1, 1024, 0, stream>>>(y, rank);
  x_pool<<<N_NODES, 256, 0, stream>>>(X, y, rank, out0);
  gather_both<<<dim3(N_NODES / 64, N_NODES / 64), 256, 0, stream>>>(A, rank, Abf8, Bt8);
  gemm_fp8<<<dim3(K_SEL / 256, K_SEL / 256), 512, 0, stream>>>(Abf8, Bt8, out1);
}